// Round 4
// baseline (526.459 us; speedup 1.0000x reference)
//
#include <hip/hip_runtime.h>

typedef __attribute__((ext_vector_type(8))) short s16x8;      // 8 bf16 (4 VGPRs) - MFMA A/B frag
typedef __attribute__((ext_vector_type(8))) unsigned short u16x8;
typedef __attribute__((ext_vector_type(4))) float f32x4;      // MFMA C/D frag + vector loads

#define B_   64
#define N_   1024
#define CIN_ 16
#define CH_  64
#define CO_  32

// round-to-nearest-even fp32 -> bf16 bits (known-good from round 1)
__device__ __forceinline__ unsigned short f2bf(float f){
  unsigned int u = __float_as_uint(f);
  u += 0x7fffu + ((u >> 16) & 1u);
  return (unsigned short)(u >> 16);
}

// ---------------------------------------------------------------------------
// linear1: H1T[b][h][n] = bf16( x[b,n,:] @ W1[h,:] + b1[h] )   (transposed store)
// ---------------------------------------------------------------------------
__global__ __launch_bounds__(256) void k_linear1(
    const float* __restrict__ x, const float* __restrict__ W1,
    const float* __restrict__ b1, unsigned short* __restrict__ H1T){
  int gt   = blockIdx.x * 256 + threadIdx.x;
  int wave = gt >> 6;           // 1024 waves total
  int lane = gt & 63;
  int b    = wave >> 4;         // 16 waves per batch
  int nl0  = (wave & 15) << 6;  // row offset within batch

  const f32x4* xv = (const f32x4*)(x + ((size_t)(b * N_ + nl0 + lane)) * CIN_);
  float xr[16];
#pragma unroll
  for (int i = 0; i < 4; ++i){
    f32x4 v = xv[i];
#pragma unroll
    for (int e = 0; e < 4; ++e) xr[i*4+e] = v[e];
  }
  for (int h = 0; h < CH_; ++h){
    float acc = b1[h];
#pragma unroll
    for (int c = 0; c < CIN_; ++c) acc += xr[c] * W1[h * CIN_ + c];
    H1T[((size_t)(b * CH_ + h)) * N_ + nl0 + lane] = f2bf(acc);
  }
}

// ---------------------------------------------------------------------------
// prop1 (barrier-free K-loop): wave w of block (b,mblk) owns rows m0+w*16..+15.
//   A-frag: graph row gn, 8 fp32 direct from global (nontemporal), +I on diag,
//           deg accumulated in fp32 from pre-conversion values.
//   B-frag: H1T row h, 8 bf16 direct from global (L2/L3-resident).
//   C = Ĝ@H1 -> relu(C*ideg) -> per-wave LDS transpose -> O1 = H2@W2^T + b2.
// ---------------------------------------------------------------------------
__global__ __launch_bounds__(256) void k_prop1(
    const float* __restrict__ graph, const unsigned short* __restrict__ H1T,
    const float* __restrict__ W2, const float* __restrict__ b2,
    unsigned short* __restrict__ O1T){
  __shared__ unsigned short sH2[4][16 * 64];   // 2KB per wave

  const int b    = blockIdx.x >> 4;
  const int m0   = (blockIdx.x & 15) << 6;
  const int tid  = threadIdx.x;
  const int w    = tid >> 6, lane = tid & 63;
  const int l15  = lane & 15, lk = lane >> 4;
  const int gn   = m0 + (w << 4) + l15;        // this lane's graph row
  const int ksd  = (m0 + (w << 4)) >> 5;       // wave-uniform diag K-chunk

  const float* gA = graph + ((size_t)b << 20) + ((size_t)gn << 10) + (lk << 3);
  const unsigned short* hB = H1T + (size_t)(b * CH_ + l15) * N_ + (lk << 3);

  f32x4 acc[4] = {{0,0,0,0},{0,0,0,0},{0,0,0,0},{0,0,0,0}};
  float deg = 0.f;

  // prefetch ks=0
  f32x4 a0 = __builtin_nontemporal_load((const f32x4*)(gA));
  f32x4 a1 = __builtin_nontemporal_load((const f32x4*)(gA + 4));
  u16x8 b0 = *(const u16x8*)(hB);
  u16x8 b1f = *(const u16x8*)(hB + 16 * N_);
  u16x8 b2f = *(const u16x8*)(hB + 32 * N_);
  u16x8 b3f = *(const u16x8*)(hB + 48 * N_);

  for (int ks = 0; ks < 32; ++ks){
    const int kn = (((ks + 1) & 31) << 5);     // next chunk (wraps; tail discard)
    f32x4 na0 = __builtin_nontemporal_load((const f32x4*)(gA + kn));
    f32x4 na1 = __builtin_nontemporal_load((const f32x4*)(gA + kn + 4));
    u16x8 nb0 = *(const u16x8*)(hB + kn);
    u16x8 nb1 = *(const u16x8*)(hB + 16 * N_ + kn);
    u16x8 nb2 = *(const u16x8*)(hB + 32 * N_ + kn);
    u16x8 nb3 = *(const u16x8*)(hB + 48 * N_ + kn);

    float va[8] = {a0[0], a0[1], a0[2], a0[3], a1[0], a1[1], a1[2], a1[3]};
    if (ks == ksd){                            // wave-uniform branch, 1 of 32 iters
      const int d0 = (ks << 5) + (lk << 3);
#pragma unroll
      for (int e = 0; e < 8; ++e) va[e] += (d0 + e == gn) ? 1.f : 0.f;
    }
#pragma unroll
    for (int e = 0; e < 8; ++e) deg += va[e];
    s16x8 af;
#pragma unroll
    for (int e = 0; e < 8; ++e) af[e] = (short)f2bf(va[e]);

    acc[0] = __builtin_amdgcn_mfma_f32_16x16x32_bf16(af, (s16x8)b0,  acc[0], 0, 0, 0);
    acc[1] = __builtin_amdgcn_mfma_f32_16x16x32_bf16(af, (s16x8)b1f, acc[1], 0, 0, 0);
    acc[2] = __builtin_amdgcn_mfma_f32_16x16x32_bf16(af, (s16x8)b2f, acc[2], 0, 0, 0);
    acc[3] = __builtin_amdgcn_mfma_f32_16x16x32_bf16(af, (s16x8)b3f, acc[3], 0, 0, 0);

    a0 = na0; a1 = na1; b0 = nb0; b1f = nb1; b2f = nb2; b3f = nb3;
  }

  // deg: lanes lk=0..3 partition row l15's k-range -> reduce across lk
  deg += __shfl_xor(deg, 16);
  deg += __shfl_xor(deg, 32);
  float ideg = 1.f / deg;                      // lane holds ideg for row l15
  float idv[4];
#pragma unroll
  for (int j = 0; j < 4; ++j) idv[j] = __shfl(ideg, (lk << 2) + j);  // for C rows lk*4+j

  // H2 = relu(C*ideg) -> per-wave LDS (swizzled), then A-frag read
#pragma unroll
  for (int cf = 0; cf < 4; ++cf){
#pragma unroll
    for (int j = 0; j < 4; ++j){
      float hv = acc[cf][j] * idv[j];
      hv = hv > 0.f ? hv : 0.f;
      int row = (lk << 2) + j;
      int col = (cf << 4) + l15;
      sH2[w][(row << 6) + (col ^ ((row & 7) << 3))] = f2bf(hv);
    }
  }
  __syncthreads();
  s16x8 a2[2];
#pragma unroll
  for (int kk = 0; kk < 2; ++kk)
    a2[kk] = *(const s16x8*)&sH2[w][(l15 << 6) + (((kk << 5) + (lk << 3)) ^ ((l15 & 7) << 3))];

  // fused linear2: O1[16x32] = H2[16x64] @ W2^T + b2
  f32x4 acc2[2] = {{0,0,0,0},{0,0,0,0}};
#pragma unroll
  for (int kk = 0; kk < 2; ++kk){
#pragma unroll
    for (int cf = 0; cf < 2; ++cf){
      const f32x4* wp = (const f32x4*)(W2 + ((cf << 4) + l15) * CH_ + (kk << 5) + (lk << 3));
      f32x4 w0 = wp[0], w1 = wp[1];
      s16x8 bw;
#pragma unroll
      for (int e = 0; e < 4; ++e){ bw[e] = (short)f2bf(w0[e]); bw[4 + e] = (short)f2bf(w1[e]); }
      acc2[cf] = __builtin_amdgcn_mfma_f32_16x16x32_bf16(a2[kk], bw, acc2[cf], 0, 0, 0);
    }
  }
#pragma unroll
  for (int cf = 0; cf < 2; ++cf){
    float badd = b2[(cf << 4) + l15];
#pragma unroll
    for (int j = 0; j < 4; ++j){
      float v = acc2[cf][j] + badd;            // NO relu here (relu after prop2)
      int n = m0 + (w << 4) + (lk << 2) + j;
      O1T[((size_t)(b * CO_ + (cf << 4) + l15)) * N_ + n] = f2bf(v);
    }
  }
}

// ---------------------------------------------------------------------------
// prop2 (barrier-free, no LDS): out = relu( ideg * Ĝ @ O1 ), deg recomputed
// bit-identically to prop1 (same loads, same add order).
// ---------------------------------------------------------------------------
__global__ __launch_bounds__(256) void k_prop2(
    const float* __restrict__ graph, const unsigned short* __restrict__ O1T,
    float* __restrict__ out){
  const int b    = blockIdx.x >> 4;
  const int m0   = (blockIdx.x & 15) << 6;
  const int tid  = threadIdx.x;
  const int w    = tid >> 6, lane = tid & 63;
  const int l15  = lane & 15, lk = lane >> 4;
  const int gn   = m0 + (w << 4) + l15;
  const int ksd  = (m0 + (w << 4)) >> 5;

  const float* gA = graph + ((size_t)b << 20) + ((size_t)gn << 10) + (lk << 3);
  const unsigned short* oB = O1T + (size_t)(b * CO_ + l15) * N_ + (lk << 3);

  f32x4 acc[2] = {{0,0,0,0},{0,0,0,0}};
  float deg = 0.f;

  f32x4 a0 = __builtin_nontemporal_load((const f32x4*)(gA));
  f32x4 a1 = __builtin_nontemporal_load((const f32x4*)(gA + 4));
  u16x8 b0 = *(const u16x8*)(oB);
  u16x8 b1f = *(const u16x8*)(oB + 16 * N_);

  for (int ks = 0; ks < 32; ++ks){
    const int kn = (((ks + 1) & 31) << 5);
    f32x4 na0 = __builtin_nontemporal_load((const f32x4*)(gA + kn));
    f32x4 na1 = __builtin_nontemporal_load((const f32x4*)(gA + kn + 4));
    u16x8 nb0 = *(const u16x8*)(oB + kn);
    u16x8 nb1 = *(const u16x8*)(oB + 16 * N_ + kn);

    float va[8] = {a0[0], a0[1], a0[2], a0[3], a1[0], a1[1], a1[2], a1[3]};
    if (ks == ksd){
      const int d0 = (ks << 5) + (lk << 3);
#pragma unroll
      for (int e = 0; e < 8; ++e) va[e] += (d0 + e == gn) ? 1.f : 0.f;
    }
#pragma unroll
    for (int e = 0; e < 8; ++e) deg += va[e];
    s16x8 af;
#pragma unroll
    for (int e = 0; e < 8; ++e) af[e] = (short)f2bf(va[e]);

    acc[0] = __builtin_amdgcn_mfma_f32_16x16x32_bf16(af, (s16x8)b0,  acc[0], 0, 0, 0);
    acc[1] = __builtin_amdgcn_mfma_f32_16x16x32_bf16(af, (s16x8)b1f, acc[1], 0, 0, 0);

    a0 = na0; a1 = na1; b0 = nb0; b1f = nb1;
  }

  deg += __shfl_xor(deg, 16);
  deg += __shfl_xor(deg, 32);
  float ideg = 1.f / deg;
  float idv[4];
#pragma unroll
  for (int j = 0; j < 4; ++j) idv[j] = __shfl(ideg, (lk << 2) + j);

#pragma unroll
  for (int cf = 0; cf < 2; ++cf){
#pragma unroll
    for (int j = 0; j < 4; ++j){
      float v = acc[cf][j] * idv[j];
      v = v > 0.f ? v : 0.f;
      int n = m0 + (w << 4) + (lk << 2) + j;
      out[((size_t)(b * N_ + n)) * CO_ + (cf << 4) + l15] = v;
    }
  }
}

// ---------------------------------------------------------------------------
extern "C" void kernel_launch(void* const* d_in, const int* in_sizes, int n_in,
                              void* d_out, int out_size, void* d_ws, size_t ws_size,
                              hipStream_t stream){
  (void)in_sizes; (void)n_in; (void)out_size; (void)ws_size;
  const float* x     = (const float*)d_in[0];
  const float* graph = (const float*)d_in[1];
  const float* W1    = (const float*)d_in[2];
  const float* b1    = (const float*)d_in[3];
  const float* W2    = (const float*)d_in[4];
  const float* b2    = (const float*)d_in[5];
  float* out = (float*)d_out;

  // ws layout: H1T bf16 [64][64][1024] = 8MB | O1T bf16 [64][32][1024] = 4MB
  unsigned short* H1T = (unsigned short*)d_ws;
  unsigned short* O1T = (unsigned short*)((char*)d_ws + ((size_t)8 << 20));

  k_linear1<<<256, 256, 0, stream>>>(x, W1, b1, H1T);
  k_prop1<<<B_ * 16, 256, 0, stream>>>(graph, H1T, W2, b2, O1T);
  k_prop2<<<B_ * 16, 256, 0, stream>>>(graph, O1T, out);
}

// Round 5
// 507.286 us; speedup vs baseline: 1.0378x; 1.0378x over previous
//
#include <hip/hip_runtime.h>

typedef __attribute__((ext_vector_type(8))) short s16x8;      // 8 bf16 (4 VGPRs) - MFMA A/B frag
typedef __attribute__((ext_vector_type(8))) unsigned short u16x8;
typedef __attribute__((ext_vector_type(4))) float f32x4;      // MFMA C/D frag + vector loads

#define B_   64
#define N_   1024
#define CIN_ 16
#define CH_  64
#define CO_  32

// round-to-nearest-even fp32 -> bf16 bits
__device__ __forceinline__ unsigned short f2bf(float f){
  unsigned int u = __float_as_uint(f);
  u += 0x7fffu + ((u >> 16) & 1u);
  return (unsigned short)(u >> 16);
}

// ---------------------------------------------------------------------------
// linear1: H1T[b][h][n] = bf16( x[b,n,:] @ W1[h,:] + b1[h] )   (transposed store)
// ---------------------------------------------------------------------------
__global__ __launch_bounds__(256) void k_linear1(
    const float* __restrict__ x, const float* __restrict__ W1,
    const float* __restrict__ b1, unsigned short* __restrict__ H1T){
  int gt   = blockIdx.x * 256 + threadIdx.x;
  int wave = gt >> 6;           // 1024 waves total
  int lane = gt & 63;
  int b    = wave >> 4;         // 16 waves per batch
  int nl0  = (wave & 15) << 6;  // row offset within batch

  const f32x4* xv = (const f32x4*)(x + ((size_t)(b * N_ + nl0 + lane)) * CIN_);
  float xr[16];
#pragma unroll
  for (int i = 0; i < 4; ++i){
    f32x4 v = xv[i];
#pragma unroll
    for (int e = 0; e < 4; ++e) xr[i*4+e] = v[e];
  }
  for (int h = 0; h < CH_; ++h){
    float acc = b1[h];
#pragma unroll
    for (int c = 0; c < CIN_; ++c) acc += xr[c] * W1[h * CIN_ + c];
    H1T[((size_t)(b * CH_ + h)) * N_ + nl0 + lane] = f2bf(acc);
  }
}

// ---------------------------------------------------------------------------
// prop1: barrier-free K-loop, direct-from-global MFMA frags.
//   A-frag: graph row gn fp32 (NT: single-use, keep out of L3) -> +I -> bf16.
//   Side outputs: GbT = bf16(Ĝraw) fragments (prop2's A input, L3-resident),
//                 idegw = 1/deg per row.
//   C = Ĝ@H1 -> relu(C*ideg) -> per-wave LDS transpose -> O1 = H2@W2^T + b2.
// ---------------------------------------------------------------------------
__global__ __launch_bounds__(256) void k_prop1(
    const float* __restrict__ graph, const unsigned short* __restrict__ H1T,
    const float* __restrict__ W2, const float* __restrict__ b2,
    unsigned short* __restrict__ O1T, unsigned short* __restrict__ GbT,
    float* __restrict__ idegw){
  __shared__ unsigned short sH2[4][16 * 64];   // 2KB per wave

  const int b    = blockIdx.x >> 4;
  const int m0   = (blockIdx.x & 15) << 6;
  const int tid  = threadIdx.x;
  const int w    = tid >> 6, lane = tid & 63;
  const int l15  = lane & 15, lk = lane >> 4;
  const int gn   = m0 + (w << 4) + l15;        // this lane's graph row
  const int ksd  = (m0 + (w << 4)) >> 5;       // wave-uniform diag K-chunk

  const float* gA = graph + ((size_t)b << 20) + ((size_t)gn << 10) + (lk << 3);
  const unsigned short* hB = H1T + (size_t)(b * CH_ + l15) * N_ + (lk << 3);
  unsigned short* gW = GbT + ((size_t)b << 20) + ((size_t)gn << 10) + (lk << 3);

  f32x4 acc[4] = {{0,0,0,0},{0,0,0,0},{0,0,0,0},{0,0,0,0}};
  float deg = 0.f;

  // prefetch ks=0
  f32x4 a0 = __builtin_nontemporal_load((const f32x4*)(gA));
  f32x4 a1 = __builtin_nontemporal_load((const f32x4*)(gA + 4));
  u16x8 b0 = *(const u16x8*)(hB);
  u16x8 b1f = *(const u16x8*)(hB + 16 * N_);
  u16x8 b2f = *(const u16x8*)(hB + 32 * N_);
  u16x8 b3f = *(const u16x8*)(hB + 48 * N_);

  for (int ks = 0; ks < 32; ++ks){
    const int kn = (((ks + 1) & 31) << 5);     // next chunk (wraps; tail discard)
    f32x4 na0 = __builtin_nontemporal_load((const f32x4*)(gA + kn));
    f32x4 na1 = __builtin_nontemporal_load((const f32x4*)(gA + kn + 4));
    u16x8 nb0 = *(const u16x8*)(hB + kn);
    u16x8 nb1 = *(const u16x8*)(hB + 16 * N_ + kn);
    u16x8 nb2 = *(const u16x8*)(hB + 32 * N_ + kn);
    u16x8 nb3 = *(const u16x8*)(hB + 48 * N_ + kn);

    float va[8] = {a0[0], a0[1], a0[2], a0[3], a1[0], a1[1], a1[2], a1[3]};
    if (ks == ksd){                            // wave-uniform branch, 1 of 32 iters
      const int d0 = (ks << 5) + (lk << 3);
#pragma unroll
      for (int e = 0; e < 8; ++e) va[e] += (d0 + e == gn) ? 1.f : 0.f;
    }
#pragma unroll
    for (int e = 0; e < 8; ++e) deg += va[e];
    s16x8 af;
#pragma unroll
    for (int e = 0; e < 8; ++e) af[e] = (short)f2bf(va[e]);

    *(s16x8*)(gW + (ks << 5)) = af;            // GbT fragment (prop2's A input)

    acc[0] = __builtin_amdgcn_mfma_f32_16x16x32_bf16(af, (s16x8)b0,  acc[0], 0, 0, 0);
    acc[1] = __builtin_amdgcn_mfma_f32_16x16x32_bf16(af, (s16x8)b1f, acc[1], 0, 0, 0);
    acc[2] = __builtin_amdgcn_mfma_f32_16x16x32_bf16(af, (s16x8)b2f, acc[2], 0, 0, 0);
    acc[3] = __builtin_amdgcn_mfma_f32_16x16x32_bf16(af, (s16x8)b3f, acc[3], 0, 0, 0);

    a0 = na0; a1 = na1; b0 = nb0; b1f = nb1; b2f = nb2; b3f = nb3;
  }

  // deg: lanes lk=0..3 partition row l15's k-range -> reduce across lk
  deg += __shfl_xor(deg, 16);
  deg += __shfl_xor(deg, 32);
  float ideg = 1.f / deg;                      // lane holds ideg for its row gn
  if (lk == 0) idegw[(b << 10) + gn] = ideg;
  float idv[4];
#pragma unroll
  for (int j = 0; j < 4; ++j) idv[j] = __shfl(ideg, (lk << 2) + j);  // for C rows lk*4+j

  // H2 = relu(C*ideg) -> per-wave LDS (swizzled), then A-frag read
#pragma unroll
  for (int cf = 0; cf < 4; ++cf){
#pragma unroll
    for (int j = 0; j < 4; ++j){
      float hv = acc[cf][j] * idv[j];
      hv = hv > 0.f ? hv : 0.f;
      int row = (lk << 2) + j;
      int col = (cf << 4) + l15;
      sH2[w][(row << 6) + (col ^ ((row & 7) << 3))] = f2bf(hv);
    }
  }
  __syncthreads();
  s16x8 a2[2];
#pragma unroll
  for (int kk = 0; kk < 2; ++kk)
    a2[kk] = *(const s16x8*)&sH2[w][(l15 << 6) + (((kk << 5) + (lk << 3)) ^ ((l15 & 7) << 3))];

  // fused linear2: O1[16x32] = H2[16x64] @ W2^T + b2
  f32x4 acc2[2] = {{0,0,0,0},{0,0,0,0}};
#pragma unroll
  for (int kk = 0; kk < 2; ++kk){
#pragma unroll
    for (int cf = 0; cf < 2; ++cf){
      const f32x4* wp = (const f32x4*)(W2 + ((cf << 4) + l15) * CH_ + (kk << 5) + (lk << 3));
      f32x4 w0 = wp[0], w1 = wp[1];
      s16x8 bw;
#pragma unroll
      for (int e = 0; e < 4; ++e){ bw[e] = (short)f2bf(w0[e]); bw[4 + e] = (short)f2bf(w1[e]); }
      acc2[cf] = __builtin_amdgcn_mfma_f32_16x16x32_bf16(a2[kk], bw, acc2[cf], 0, 0, 0);
    }
  }
#pragma unroll
  for (int cf = 0; cf < 2; ++cf){
    float badd = b2[(cf << 4) + l15];
#pragma unroll
    for (int j = 0; j < 4; ++j){
      float v = acc2[cf][j] + badd;            // NO relu here (relu after prop2)
      int n = m0 + (w << 4) + (lk << 2) + j;
      O1T[((size_t)(b * CO_ + (cf << 4) + l15)) * N_ + n] = f2bf(v);
    }
  }
}

// ---------------------------------------------------------------------------
// prop2: out = relu( ideg * Ĝ @ O1 ) with Ĝ read as bf16 from GbT (L3-hot),
// no conversions, no deg recompute. Descending k (newest-written first),
// depth-2 prefetch.
// ---------------------------------------------------------------------------
__global__ __launch_bounds__(256) void k_prop2(
    const unsigned short* __restrict__ GbT, const unsigned short* __restrict__ O1T,
    const float* __restrict__ idegw, float* __restrict__ out){
  const int b    = blockIdx.x >> 4;
  const int m0   = (blockIdx.x & 15) << 6;
  const int tid  = threadIdx.x;
  const int w    = tid >> 6, lane = tid & 63;
  const int l15  = lane & 15, lk = lane >> 4;
  const int gn   = m0 + (w << 4) + l15;

  const unsigned short* gA = GbT + ((size_t)b << 20) + ((size_t)gn << 10) + (lk << 3);
  const unsigned short* oB = O1T + (size_t)(b * CO_ + l15) * N_ + (lk << 3);

  f32x4 acc[2] = {{0,0,0,0},{0,0,0,0}};

  // depth-2 prefetch, descending k: slot0 = ks, slot1 = ks-1
  u16x8 aP0 = *(const u16x8*)(gA + (31 << 5));
  u16x8 bP0 = *(const u16x8*)(oB + (31 << 5));
  u16x8 cP0 = *(const u16x8*)(oB + 16 * N_ + (31 << 5));
  u16x8 aP1 = *(const u16x8*)(gA + (30 << 5));
  u16x8 bP1 = *(const u16x8*)(oB + (30 << 5));
  u16x8 cP1 = *(const u16x8*)(oB + 16 * N_ + (30 << 5));

#pragma unroll 4
  for (int ks = 31; ks >= 0; --ks){
    const int kn = ((ks + 30) & 31) << 5;      // ks-2 mod 32 (tail wraps; discarded)
    u16x8 na = *(const u16x8*)(gA + kn);
    u16x8 nb = *(const u16x8*)(oB + kn);
    u16x8 nc = *(const u16x8*)(oB + 16 * N_ + kn);

    acc[0] = __builtin_amdgcn_mfma_f32_16x16x32_bf16((s16x8)aP0, (s16x8)bP0, acc[0], 0, 0, 0);
    acc[1] = __builtin_amdgcn_mfma_f32_16x16x32_bf16((s16x8)aP0, (s16x8)cP0, acc[1], 0, 0, 0);

    aP0 = aP1; bP0 = bP1; cP0 = cP1;
    aP1 = na;  bP1 = nb;  cP1 = nc;
  }

  f32x4 idv = *(const f32x4*)(idegw + (b << 10) + m0 + (w << 4) + (lk << 2));

#pragma unroll
  for (int cf = 0; cf < 2; ++cf){
#pragma unroll
    for (int j = 0; j < 4; ++j){
      float v = acc[cf][j] * idv[j];
      v = v > 0.f ? v : 0.f;
      int n = m0 + (w << 4) + (lk << 2) + j;
      out[((size_t)(b * N_ + n)) * CO_ + (cf << 4) + l15] = v;
    }
  }
}

// ---------------------------------------------------------------------------
extern "C" void kernel_launch(void* const* d_in, const int* in_sizes, int n_in,
                              void* d_out, int out_size, void* d_ws, size_t ws_size,
                              hipStream_t stream){
  (void)in_sizes; (void)n_in; (void)out_size; (void)ws_size;
  const float* x     = (const float*)d_in[0];
  const float* graph = (const float*)d_in[1];
  const float* W1    = (const float*)d_in[2];
  const float* b1    = (const float*)d_in[3];
  const float* W2    = (const float*)d_in[4];
  const float* b2    = (const float*)d_in[5];
  float* out = (float*)d_out;

  // ws: H1T bf16 8MB | O1T bf16 4MB | idegw f32 256KB(+pad) | GbT bf16 128MB
  unsigned short* H1T = (unsigned short*)d_ws;
  unsigned short* O1T = (unsigned short*)((char*)d_ws + ((size_t)8 << 20));
  float*        idegw = (float*)((char*)d_ws + ((size_t)12 << 20));
  unsigned short* GbT = (unsigned short*)((char*)d_ws + ((size_t)16 << 20));

  k_linear1<<<256, 256, 0, stream>>>(x, W1, b1, H1T);
  k_prop1<<<B_ * 16, 256, 0, stream>>>(graph, H1T, W2, b2, O1T, GbT, idegw);
  k_prop2<<<B_ * 16, 256, 0, stream>>>(GbT, O1T, idegw, out);
}

// Round 6
// 473.789 us; speedup vs baseline: 1.1112x; 1.0707x over previous
//
#include <hip/hip_runtime.h>

typedef __attribute__((ext_vector_type(8))) short s16x8;      // 8 bf16 MFMA A/B frag
typedef __attribute__((ext_vector_type(8))) unsigned short u16x8;
typedef __attribute__((ext_vector_type(4))) unsigned short u16x4;
typedef __attribute__((ext_vector_type(4))) float f32x4;

#define B_   64
#define N_   1024
#define CIN_ 16
#define CH_  64
#define CO_  32

__device__ __forceinline__ unsigned short f2bf(float f){
  unsigned int u = __float_as_uint(f);
  u += 0x7fffu + ((u >> 16) & 1u);
  return (unsigned short)(u >> 16);
}

// ---------------------------------------------------------------------------
// linear1: H1T[b][h][n] = bf16( x[b,n,:] @ W1[h,:] + b1[h] )
// ---------------------------------------------------------------------------
__global__ __launch_bounds__(256) void k_linear1(
    const float* __restrict__ x, const float* __restrict__ W1,
    const float* __restrict__ b1, unsigned short* __restrict__ H1T){
  int gt   = blockIdx.x * 256 + threadIdx.x;
  int wave = gt >> 6, lane = gt & 63;
  int b    = wave >> 4;
  int nl0  = (wave & 15) << 6;

  const f32x4* xv = (const f32x4*)(x + ((size_t)(b * N_ + nl0 + lane)) * CIN_);
  float xr[16];
#pragma unroll
  for (int i = 0; i < 4; ++i){
    f32x4 v = xv[i];
#pragma unroll
    for (int e = 0; e < 4; ++e) xr[i*4+e] = v[e];
  }
  for (int h = 0; h < CH_; ++h){
    float acc = b1[h];
#pragma unroll
    for (int c = 0; c < CIN_; ++c) acc += xr[c] * W1[h * CIN_ + c];
    H1T[((size_t)(b * CH_ + h)) * N_ + nl0 + lane] = f2bf(acc);
  }
}

// ---------------------------------------------------------------------------
// convert: LINEAR read of graph fp32 (wave = 256 contiguous floats, one row),
// +I, fp32 quarter-row degree partials, bf16 write to tiled+swizzled GbT:
//   GbT[b][mtile][ks][srow][c8s][8], c8s = c8 ^ (srow&7)  (T2 involution)
// ---------------------------------------------------------------------------
__global__ __launch_bounds__(256) void k_convert(
    const float* __restrict__ graph, unsigned short* __restrict__ GbT,
    float* __restrict__ degp){
  const int t    = blockIdx.x * 256 + threadIdx.x;   // 524288 threads
  const int lane = threadIdx.x & 63;

  size_t i  = (size_t)t;                              // f32x4 index
  f32x4 v   = *(const f32x4*)(graph + (i << 2));      // prefetch iter 0
  for (int it = 0; it < 32; ++it){
    size_t inext = (size_t)t + (size_t)((it + 1) & 31) * 524288;
    f32x4 vn = *(const f32x4*)(graph + (inext << 2)); // next iter (wraps; discarded)

    const size_t fbase   = i << 2;
    const int rowflat    = (int)(fbase >> 10);
    const int row_in_b   = rowflat & 1023;
    const int c0         = (int)(fbase & 1023);
    const int d          = row_in_b - c0;
    if (d >= 0 && d < 4) v[d] += 1.f;                 // +I (per-lane, rare)

    float s = v[0] + v[1] + v[2] + v[3];
    s += __shfl_xor(s, 1);  s += __shfl_xor(s, 2);  s += __shfl_xor(s, 4);
    s += __shfl_xor(s, 8);  s += __shfl_xor(s, 16); s += __shfl_xor(s, 32);
    if (lane == 0) degp[(size_t)rowflat * 4 + ((c0 >> 8) & 3)] = s;

    const int b     = rowflat >> 10;
    const int mtile = row_in_b >> 6, srow = row_in_b & 63;
    const int ks    = c0 >> 6,       colt = c0 & 63;
    const int c8s   = (colt >> 3) ^ (srow & 7);
    const size_t dst = ((((size_t)(b * 16 + mtile) * 16 + ks) * 64 + srow) * 8 + c8s) * 8
                       + (colt & 7);
    u16x4 o;
#pragma unroll
    for (int e = 0; e < 4; ++e) o[e] = f2bf(v[e]);
    *(u16x4*)(GbT + dst) = o;

    i = inext; v = vn;
  }
}

// ---------------------------------------------------------------------------
// ideg: idegw[row] = 1 / sum(degp[row][0..3])
// ---------------------------------------------------------------------------
__global__ __launch_bounds__(256) void k_ideg(
    const float* __restrict__ degp, float* __restrict__ idegw){
  int i = blockIdx.x * 256 + threadIdx.x;            // 65536
  f32x4 d = *(const f32x4*)(degp + (size_t)i * 4);
  idegw[i] = 1.f / (d[0] + d[1] + d[2] + d[3]);
}

// ---------------------------------------------------------------------------
// prop1: C = Ĝ@H1 via LDS double-buffer (1 barrier/step). A-tile: one LINEAR
// 8KB chunk of GbT per K-step (swizzle pre-baked). B-tile: H1T rows with
// source-side swizzle. Then relu(C*ideg) -> sH2 transpose -> O1 = H2@W2^T+b2.
// ---------------------------------------------------------------------------
__global__ __launch_bounds__(256) void k_prop1(
    const unsigned short* __restrict__ GbT, const unsigned short* __restrict__ H1T,
    const float* __restrict__ W2, const float* __restrict__ b2,
    const float* __restrict__ idegw, unsigned short* __restrict__ O1T){
  __shared__ unsigned short sA[2][4096];
  __shared__ unsigned short sB[2][4096];
  __shared__ unsigned short sH2[4][1024];

  const int b = blockIdx.x >> 4, mtile = blockIdx.x & 15, m0 = mtile << 6;
  const int tid = threadIdx.x, w = tid >> 6, lane = tid & 63;
  const int l15 = lane & 15, lk = lane >> 4;

  const unsigned short* gA = GbT + ((size_t)(b * 16 + mtile) << 16);
  const unsigned short* hB = H1T + ((size_t)b << 16);

  const int ch0 = tid, ch1 = 256 + tid;
  const int r0 = ch0 >> 3, r1 = ch1 >> 3;
  const size_t bs0 = (size_t)r0 * N_ + (((ch0 & 7) ^ (r0 & 7)) << 3);
  const size_t bs1 = (size_t)r1 * N_ + (((ch1 & 7) ^ (r1 & 7)) << 3);

  f32x4 acc[4] = {{0,0,0,0},{0,0,0,0},{0,0,0,0},{0,0,0,0}};

  // prologue: stage ks=0 into buf 0
  {
    u16x8 a0 = *(const u16x8*)(gA + ch0 * 8);
    u16x8 a1 = *(const u16x8*)(gA + ch1 * 8);
    u16x8 h0 = *(const u16x8*)(hB + bs0);
    u16x8 h1 = *(const u16x8*)(hB + bs1);
    *(u16x8*)&sA[0][ch0 * 8] = a0;  *(u16x8*)&sA[0][ch1 * 8] = a1;
    *(u16x8*)&sB[0][ch0 * 8] = h0;  *(u16x8*)&sB[0][ch1 * 8] = h1;
  }
  __syncthreads();

  int buf = 0;
  const int arow = (w << 4) + l15;
  for (int ks = 0; ks < 16; ++ks){
    const int kn = (ks + 1) & 15;               // wraps; tail writes skipped
    u16x8 na0 = *(const u16x8*)(gA + (size_t)kn * 4096 + ch0 * 8);
    u16x8 na1 = *(const u16x8*)(gA + (size_t)kn * 4096 + ch1 * 8);
    u16x8 nh0 = *(const u16x8*)(hB + bs0 + kn * 64);
    u16x8 nh1 = *(const u16x8*)(hB + bs1 + kn * 64);

#pragma unroll
    for (int kk = 0; kk < 2; ++kk){
      s16x8 a = *(const s16x8*)&sA[buf][arow * 64 + ((((kk << 2) + lk) ^ (arow & 7)) << 3)];
#pragma unroll
      for (int cf = 0; cf < 4; ++cf){
        const int brow = (cf << 4) + l15;
        s16x8 bb = *(const s16x8*)&sB[buf][brow * 64 + ((((kk << 2) + lk) ^ (brow & 7)) << 3)];
        acc[cf] = __builtin_amdgcn_mfma_f32_16x16x32_bf16(a, bb, acc[cf], 0, 0, 0);
      }
    }
    if (ks < 15){
      *(u16x8*)&sA[buf ^ 1][ch0 * 8] = na0;  *(u16x8*)&sA[buf ^ 1][ch1 * 8] = na1;
      *(u16x8*)&sB[buf ^ 1][ch0 * 8] = nh0;  *(u16x8*)&sB[buf ^ 1][ch1 * 8] = nh1;
    }
    __syncthreads();
    buf ^= 1;
  }

  // ideg scale + relu -> sH2 (per-wave transpose), rows of C: lk*4+j
  f32x4 idv = *(const f32x4*)(idegw + (b << 10) + m0 + (w << 4) + (lk << 2));
#pragma unroll
  for (int cf = 0; cf < 4; ++cf){
#pragma unroll
    for (int j = 0; j < 4; ++j){
      float hv = acc[cf][j] * idv[j];
      hv = hv > 0.f ? hv : 0.f;
      int row = (lk << 2) + j;
      int col = (cf << 4) + l15;
      sH2[w][(row << 6) + (col ^ ((row & 7) << 3))] = f2bf(hv);
    }
  }
  __syncthreads();
  s16x8 a2[2];
#pragma unroll
  for (int kk = 0; kk < 2; ++kk)
    a2[kk] = *(const s16x8*)&sH2[w][(l15 << 6) + (((kk << 5) + (lk << 3)) ^ ((l15 & 7) << 3))];

  // fused linear2: O1[16x32] = H2[16x64] @ W2^T + b2
  f32x4 acc2[2] = {{0,0,0,0},{0,0,0,0}};
#pragma unroll
  for (int kk = 0; kk < 2; ++kk){
#pragma unroll
    for (int cf = 0; cf < 2; ++cf){
      const f32x4* wp = (const f32x4*)(W2 + ((cf << 4) + l15) * CH_ + (kk << 5) + (lk << 3));
      f32x4 w0 = wp[0], w1 = wp[1];
      s16x8 bw;
#pragma unroll
      for (int e = 0; e < 4; ++e){ bw[e] = (short)f2bf(w0[e]); bw[4 + e] = (short)f2bf(w1[e]); }
      acc2[cf] = __builtin_amdgcn_mfma_f32_16x16x32_bf16(a2[kk], bw, acc2[cf], 0, 0, 0);
    }
  }
#pragma unroll
  for (int cf = 0; cf < 2; ++cf){
    float badd = b2[(cf << 4) + l15];
#pragma unroll
    for (int j = 0; j < 4; ++j){
      float v = acc2[cf][j] + badd;              // relu applied after prop2
      int n = m0 + (w << 4) + (lk << 2) + j;
      O1T[((size_t)(b * CO_ + (cf << 4) + l15)) * N_ + n] = f2bf(v);
    }
  }
}

// ---------------------------------------------------------------------------
// prop2: out = relu( ideg * Ĝ @ O1 ), same structure, 32 cols.
// ---------------------------------------------------------------------------
__global__ __launch_bounds__(256) void k_prop2(
    const unsigned short* __restrict__ GbT, const unsigned short* __restrict__ O1T,
    const float* __restrict__ idegw, float* __restrict__ out){
  __shared__ unsigned short sA[2][4096];
  __shared__ unsigned short sB[2][2048];

  const int b = blockIdx.x >> 4, mtile = blockIdx.x & 15, m0 = mtile << 6;
  const int tid = threadIdx.x, w = tid >> 6, lane = tid & 63;
  const int l15 = lane & 15, lk = lane >> 4;

  const unsigned short* gA = GbT + ((size_t)(b * 16 + mtile) << 16);
  const unsigned short* oB = O1T + ((size_t)b << 15);

  const int ch0 = tid, ch1 = 256 + tid;
  const int rB = tid >> 3;                       // 0..31
  const size_t bs = (size_t)rB * N_ + (((tid & 7) ^ (rB & 7)) << 3);

  f32x4 acc[2] = {{0,0,0,0},{0,0,0,0}};

  {
    u16x8 a0 = *(const u16x8*)(gA + ch0 * 8);
    u16x8 a1 = *(const u16x8*)(gA + ch1 * 8);
    u16x8 o0 = *(const u16x8*)(oB + bs);
    *(u16x8*)&sA[0][ch0 * 8] = a0;  *(u16x8*)&sA[0][ch1 * 8] = a1;
    *(u16x8*)&sB[0][tid * 8] = o0;
  }
  __syncthreads();

  int buf = 0;
  const int arow = (w << 4) + l15;
  for (int ks = 0; ks < 16; ++ks){
    const int kn = (ks + 1) & 15;
    u16x8 na0 = *(const u16x8*)(gA + (size_t)kn * 4096 + ch0 * 8);
    u16x8 na1 = *(const u16x8*)(gA + (size_t)kn * 4096 + ch1 * 8);
    u16x8 no0 = *(const u16x8*)(oB + bs + kn * 64);

#pragma unroll
    for (int kk = 0; kk < 2; ++kk){
      s16x8 a = *(const s16x8*)&sA[buf][arow * 64 + ((((kk << 2) + lk) ^ (arow & 7)) << 3)];
#pragma unroll
      for (int cf = 0; cf < 2; ++cf){
        const int brow = (cf << 4) + l15;
        s16x8 bb = *(const s16x8*)&sB[buf][brow * 64 + ((((kk << 2) + lk) ^ (brow & 7)) << 3)];
        acc[cf] = __builtin_amdgcn_mfma_f32_16x16x32_bf16(a, bb, acc[cf], 0, 0, 0);
      }
    }
    if (ks < 15){
      *(u16x8*)&sA[buf ^ 1][ch0 * 8] = na0;  *(u16x8*)&sA[buf ^ 1][ch1 * 8] = na1;
      *(u16x8*)&sB[buf ^ 1][tid * 8] = no0;
    }
    __syncthreads();
    buf ^= 1;
  }

  f32x4 idv = *(const f32x4*)(idegw + (b << 10) + m0 + (w << 4) + (lk << 2));
#pragma unroll
  for (int cf = 0; cf < 2; ++cf){
#pragma unroll
    for (int j = 0; j < 4; ++j){
      float v = acc[cf][j] * idv[j];
      v = v > 0.f ? v : 0.f;
      int n = m0 + (w << 4) + (lk << 2) + j;
      out[((size_t)(b * N_ + n)) * CO_ + (cf << 4) + l15] = v;
    }
  }
}

// ---------------------------------------------------------------------------
extern "C" void kernel_launch(void* const* d_in, const int* in_sizes, int n_in,
                              void* d_out, int out_size, void* d_ws, size_t ws_size,
                              hipStream_t stream){
  (void)in_sizes; (void)n_in; (void)out_size; (void)ws_size;
  const float* x     = (const float*)d_in[0];
  const float* graph = (const float*)d_in[1];
  const float* W1    = (const float*)d_in[2];
  const float* b1    = (const float*)d_in[3];
  const float* W2    = (const float*)d_in[4];
  const float* b2    = (const float*)d_in[5];
  float* out = (float*)d_out;

  // ws: H1T 8MB | O1T 4MB | idegw 256KB | degp 1MB | GbT 128MB  (@16MB)
  unsigned short* H1T = (unsigned short*)d_ws;
  unsigned short* O1T = (unsigned short*)((char*)d_ws + ((size_t)8 << 20));
  float*        idegw = (float*)((char*)d_ws + ((size_t)12 << 20));
  float*         degp = (float*)((char*)d_ws + ((size_t)13 << 20));
  unsigned short* GbT = (unsigned short*)((char*)d_ws + ((size_t)16 << 20));

  k_linear1<<<256,  256, 0, stream>>>(x, W1, b1, H1T);
  k_convert<<<2048, 256, 0, stream>>>(graph, GbT, degp);
  k_ideg   <<<256,  256, 0, stream>>>(degp, idegw);
  k_prop1  <<<B_ * 16, 256, 0, stream>>>(GbT, H1T, W2, b2, idegw, O1T);
  k_prop2  <<<B_ * 16, 256, 0, stream>>>(GbT, O1T, idegw, out);
}